// Round 7
// baseline (332.039 us; speedup 1.0000x reference)
//
#include <hip/hip_runtime.h>

// ---------------------------------------------------------------------------
// AbstractNN forward on MI355X (gfx950).
// out (f32 flat): x_out[14338][2048], x_min[2048], x_max[2048], x_true_out[32][2048]
// x_out rows: 0=center@W.T+b, 1..8192=eps@W.T, 8193..12288=add_w, 12289..14336=add_b,
//             14337=noise@|W|.T
// GEMM (eps rows only, M=8192): 256x256 8-phase bf16 MFMA, balanced phases
//   (kk, m-half) -> <=8 ds_read + 16 MFMA per phase; T2 swizzle; counted vmcnt;
//   setprio; XCD-chunked block swizzle. abs-sum fused in epilogue -> gpart[0..63].
// 34 small dense rows (center, 32 x_true, noise@|W|) via wave-per-column f32 GEMV,
//   fused with one-hot scatter (extra blocks); scatter |v| -> gpart row 64.
// ---------------------------------------------------------------------------

typedef __bf16 bf16_t;
typedef bf16_t bf16x8 __attribute__((ext_vector_type(8)));
typedef float f32x4 __attribute__((ext_vector_type(4)));

#define D 2048
#define NKT 32                   // K tiles of 64
#define ROW_ADDW 8193
#define ROW_ADDB 12289
#define ROW_NOISE 14337
#define N_OUT_ROWS 14338
#define OUT_MIN ((size_t)N_OUT_ROWS * D)
#define OUT_MAX (OUT_MIN + D)
#define OUT_XTRUE (OUT_MAX + D)

#define GLOAD_LDS16(g, l)                                                 \
  __builtin_amdgcn_global_load_lds(                                       \
      (__attribute__((address_space(1))) void*)(g),                       \
      (__attribute__((address_space(3))) void*)(l), 16, 0, 0)

// swizzled LDS fragment read: region element-ptr, row (0..255), c2 = col byte offset
#define LDSF(base, row, c2)                                               \
  (*(const bf16x8*)((const char*)(base) + (row) * 128 + ((c2) ^ (((row) & 7) << 4))))

// ------------- convert: Xb (8192 eps rows) + Wb (2048) + zero absacc -------
__global__ __launch_bounds__(256) void convert_all(const float* __restrict__ x,
                                                   const float* __restrict__ W,
                                                   bf16_t* __restrict__ Xb,
                                                   bf16_t* __restrict__ Wb,
                                                   float* __restrict__ gpart) {
  const int bid = blockIdx.x;
  const int c = threadIdx.x * 8;
  if (bid == 10240) {  // zero gpart row 64 (scatter abs accumulator)
    *(float4*)(gpart + 64 * D + c) = float4{0.f, 0.f, 0.f, 0.f};
    *(float4*)(gpart + 64 * D + c + 4) = float4{0.f, 0.f, 0.f, 0.f};
    return;
  }
  const float* src;
  bf16_t* dst;
  if (bid < 8192) {                       // eps row bid <- x row bid+1
    src = x + (size_t)(bid + 1) * D + c;
    dst = Xb + (size_t)bid * D + c;
  } else {                                // W row
    src = W + (size_t)(bid - 8192) * D + c;
    dst = Wb + (size_t)(bid - 8192) * D + c;
  }
  float4 f0 = *(const float4*)(src);
  float4 f1 = *(const float4*)(src + 4);
  bf16x8 o;
  o[0] = (bf16_t)f0.x; o[1] = (bf16_t)f0.y; o[2] = (bf16_t)f0.z; o[3] = (bf16_t)f0.w;
  o[4] = (bf16_t)f1.x; o[5] = (bf16_t)f1.y; o[6] = (bf16_t)f1.z; o[7] = (bf16_t)f1.w;
  *(bf16x8*)dst = o;
}

// ----------------------- 256x256 balanced-phase bf16 GEMM ------------------
__global__ __launch_bounds__(512) void gemm8_kernel(const bf16_t* __restrict__ Xb,
                                                    const bf16_t* __restrict__ Wb,
                                                    float* __restrict__ out,
                                                    float* __restrict__ gpart) {
  __shared__ bf16_t lds[65536];  // 128 KiB: buf{0,1} x (A[256][64], B[256][64])
  const int tid = threadIdx.x;
  const int wid = tid >> 6, l = tid & 63;
  const int wm = wid >> 2, wn = wid & 3;     // 2x4 waves
  const int g4 = l >> 4, r16 = l & 15;
  // XCD-chunked swizzle (grid 8x32 = 256, dispatch f = x + y*8; XCD = f%8 owns
  // mt in [xcd*4, xcd*4+4) x all nt): bijective since 256 % 8 == 0.
  const int f = blockIdx.y * 8 + blockIdx.x;
  const int orig = (f & 7) * 32 + (f >> 3);
  const int mt = orig >> 3, nt = orig & 7;
  const int m0 = mt * 256, n0 = nt * 256;
  // staging: 512 threads x 16B = 8KB/issue (64 rows x 128B), pre-swizzled source
  const int sr = tid >> 3;
  const int scol = ((tid & 7) ^ (sr & 7)) << 3;

  f32x4 acc[8][4] = {};

#define STAGE_HALF(G, row0, k0, ldsoff)                                          \
  {                                                                              \
    const bf16_t* _s0 = (G) + (size_t)((row0) + sr) * D + (k0) + scol;           \
    const bf16_t* _s1 = (G) + (size_t)((row0) + 64 + sr) * D + (k0) + scol;      \
    GLOAD_LDS16(_s0, &lds[(ldsoff) + tid * 8]);                                  \
    GLOAD_LDS16(_s1, &lds[(ldsoff) + 4096 + tid * 8]);                           \
  }

  // ---- prologue: tile0 A+B -> buf0, tile1 B -> buf1 ----
  STAGE_HALF(Xb, m0, 0, 0);
  STAGE_HALF(Xb, m0 + 128, 0, 8192);
  STAGE_HALF(Wb, n0, 0, 16384);
  STAGE_HALF(Wb, n0 + 128, 0, 24576);
  STAGE_HALF(Wb, n0, 64, 32768 + 16384);
  STAGE_HALF(Wb, n0 + 128, 64, 32768 + 24576);
  asm volatile("s_waitcnt vmcnt(4)" ::: "memory");  // A0+B0 landed; B1 in flight
  __builtin_amdgcn_sched_barrier(0);
  __builtin_amdgcn_s_barrier();
  __builtin_amdgcn_sched_barrier(0);

  for (int t = 0; t < NKT; ++t) {
    const int bufA = (t & 1) << 15;
    const int bufN = ((t + 1) & 1) << 15;
    const int k1 = (((t + 1) & (NKT - 1)) << 6);  // wrap: harmless garbage stage
    const int k2 = (((t + 2) & (NKT - 1)) << 6);
    const bf16_t* Areg = &lds[bufA];
    const bf16_t* Breg = &lds[bufA + 16384];

    bf16x8 bb[4];   // persists across q pairs (kk=0: q0,q1; kk=1: q2,q3)
    bf16x8 a[4];

#pragma unroll
    for (int q = 0; q < 4; ++q) {
      const int kk = q >> 1;            // phase = (kk, m-half): balanced 4-8 reads
      const int mh = (q & 1) * 4;
      if ((q & 1) == 0) {               // reload B fragments at kk change
#pragma unroll
        for (int n = 0; n < 4; ++n)
          bb[n] = LDSF(Breg, wn * 64 + n * 16 + r16, kk * 64 + g4 * 16);
      }
#pragma unroll
      for (int m = 0; m < 4; ++m)
        a[m] = LDSF(Areg, wm * 128 + (mh + m) * 16 + r16, kk * 64 + g4 * 16);
      // staging: A(t+1) at q0/q1 (other buffer); B(t+2) all at q3 (its region's
      // last reads were q2's, drained by q2's pre-MFMA lgkm wait)
      if (q == 0)      STAGE_HALF(Xb, m0,       k1, bufN)
      else if (q == 1) STAGE_HALF(Xb, m0 + 128, k1, bufN + 8192)
      else if (q == 3) {
        STAGE_HALF(Wb, n0,       k2, bufA + 16384)
        STAGE_HALF(Wb, n0 + 128, k2, bufA + 24576)
      }
      __builtin_amdgcn_sched_barrier(0);
      __builtin_amdgcn_s_barrier();
      __builtin_amdgcn_sched_barrier(0);
      __builtin_amdgcn_s_setprio(1);
#pragma unroll
      for (int m = 0; m < 4; ++m)
#pragma unroll
        for (int n = 0; n < 4; ++n)
          acc[mh + m][n] = __builtin_amdgcn_mfma_f32_16x16x32_bf16(
              a[m], bb[n], acc[mh + m][n], 0, 0, 0);
      __builtin_amdgcn_s_setprio(0);
      __builtin_amdgcn_sched_barrier(0);
      if (q == 3) {  // counted vmcnt once per K-tile: B(t+2)'s 4 stay in flight
        asm volatile("s_waitcnt vmcnt(4)" ::: "memory");
        __builtin_amdgcn_sched_barrier(0);
      }
      __builtin_amdgcn_s_barrier();
      __builtin_amdgcn_sched_barrier(0);
    }
  }

  // ---- epilogue: C write (out rows 1..8192) + per-column abs partials ----
#pragma unroll
  for (int m = 0; m < 8; ++m) {
    const int grow = m0 + wm * 128 + m * 16 + g4 * 4;
#pragma unroll
    for (int n = 0; n < 4; ++n) {
      const int gc = n0 + wn * 64 + n * 16 + r16;
#pragma unroll
      for (int j = 0; j < 4; ++j)
        out[(size_t)(grow + j + 1) * D + gc] = acc[m][n][j];
    }
  }
#pragma unroll
  for (int n = 0; n < 4; ++n) {
    float s = 0.f;
#pragma unroll
    for (int m = 0; m < 8; ++m)
#pragma unroll
      for (int j = 0; j < 4; ++j)
        s += fabsf(acc[m][n][j]);
    s += __shfl_xor(s, 16, 64);
    s += __shfl_xor(s, 32, 64);
    if (g4 == 0)
      gpart[(size_t)(mt * 2 + wm) * D + n0 + wn * 64 + n * 16 + r16] = s;
  }
#undef STAGE_HALF
}

// ---- 34 small dense rows (wave-per-column f32 GEMV) + one-hot scatter -----
// blocks 0..511: 4 waves/block, wave owns out-column j = bid*4 + w.
// blocks 512..535: scatter add_w / add_b; |v| atomics into gpart row 64.
__global__ __launch_bounds__(256) void small_scatter(const float* __restrict__ x,
                                                     const float* __restrict__ x_true,
                                                     const float* __restrict__ W,
                                                     const float* __restrict__ bias,
                                                     const float* __restrict__ w_val,
                                                     const float* __restrict__ b_val,
                                                     const int* __restrict__ w_idx,
                                                     const int* __restrict__ b_idx,
                                                     float* __restrict__ out,
                                                     float* __restrict__ gpart) {
  const int bid = blockIdx.x;
  const int tid = threadIdx.x;
  if (bid < 512) {
    const int w = tid >> 6, l = tid & 63;
    const int j = bid * 4 + w;
    const float* wrow = W + (size_t)j * D;
    const float* xn = x + (size_t)8193 * D;
    float accc = 0.f, accn = 0.f;
    float acct[32] = {};
    for (int it = 0; it < 8; ++it) {
      const int k = it * 256 + l * 4;          // lane-coalesced
      float4 w4 = *(const float4*)(wrow + k);
      float4 c4 = *(const float4*)(x + k);
      accc += w4.x * c4.x + w4.y * c4.y + w4.z * c4.z + w4.w * c4.w;
      float4 n4 = *(const float4*)(xn + k);
      accn += fabsf(w4.x) * n4.x + fabsf(w4.y) * n4.y + fabsf(w4.z) * n4.z + fabsf(w4.w) * n4.w;
#pragma unroll
      for (int r = 0; r < 32; ++r) {
        float4 t4 = *(const float4*)(x_true + (size_t)r * D + k);
        acct[r] += w4.x * t4.x + w4.y * t4.y + w4.z * t4.z + w4.w * t4.w;
      }
    }
#pragma unroll
    for (int off = 32; off; off >>= 1) {
      accc += __shfl_xor(accc, off, 64);
      accn += __shfl_xor(accn, off, 64);
#pragma unroll
      for (int r = 0; r < 32; ++r) acct[r] += __shfl_xor(acct[r], off, 64);
    }
    if (l == 0) {
      const float bj = bias[j];
      out[j] = accc + bj;                          // center (+b)
      out[(size_t)ROW_NOISE * D + j] = accn;       // noise (no bias)
#pragma unroll
      for (int r = 0; r < 32; ++r)
        out[OUT_XTRUE + (size_t)r * D + j] = acct[r] + bj;
    }
    return;
  }
  // scatter blocks
  const int i = (bid - 512) * 256 + tid;
  if (i < 4096) {
    const int idx = w_idx[i];
    const int row = idx >> 11, col = idx & 2047;   // D = 2048 pow2
    const float v = w_val[i] * x[col];
    out[(size_t)(ROW_ADDW + i) * D + row] = v;
    atomicAdd(&gpart[64 * D + row], fabsf(v));
  }
  const int ib = i - 4096;
  if (ib >= 0 && ib < 2048) {
    const float v = b_val[ib];
    out[(size_t)(ROW_ADDB + ib) * D + b_idx[ib]] = v;
    atomicAdd(&gpart[64 * D + b_idx[ib]], fabsf(v));
  }
}

// ------------------------------ min / max ----------------------------------
__global__ __launch_bounds__(256) void final_minmax(const float* __restrict__ gpart,
                                                    float* __restrict__ out) {
  const int col = blockIdx.x * 256 + threadIdx.x;
  float s = 0.f;
#pragma unroll 5
  for (int p = 0; p < 65; ++p) s += gpart[(size_t)p * D + col];  // 64 GEMM + scatter
  s += fabsf(out[(size_t)ROW_NOISE * D + col]);
  const float c = out[col];
  out[OUT_MIN + col] = c - s;
  out[OUT_MAX + col] = c + s;
}

// ------------------------------- launcher ----------------------------------
extern "C" void kernel_launch(void* const* d_in, const int* in_sizes, int n_in,
                              void* d_out, int out_size, void* d_ws, size_t ws_size,
                              hipStream_t stream) {
  const float* x      = (const float*)d_in[0];
  const float* x_true = (const float*)d_in[1];
  const float* W      = (const float*)d_in[2];
  const float* b      = (const float*)d_in[3];
  const float* w_val  = (const float*)d_in[4];
  const float* b_val  = (const float*)d_in[5];
  const int*   w_idx  = (const int*)d_in[6];
  const int*   b_idx  = (const int*)d_in[7];
  float* out = (float*)d_out;

  char* ws = (char*)d_ws;
  bf16_t* Xb    = (bf16_t*)ws;                  // 8192*2048*2 = 32 MiB
  bf16_t* Wb    = (bf16_t*)(ws + 33554432);     // 8 MiB
  float*  gpart = (float*)(ws + 41943040);      // 65*2048*4 = 520 KiB

  // zero one-hot out rows (8193..14336)
  hipMemsetAsync(out + (size_t)ROW_ADDW * D, 0, (size_t)6144 * D * sizeof(float), stream);
  convert_all<<<dim3(10241), 256, 0, stream>>>(x, W, Xb, Wb, gpart);
  gemm8_kernel<<<dim3(8, 32), 512, 0, stream>>>(Xb, Wb, out, gpart);
  small_scatter<<<dim3(536), 256, 0, stream>>>(x, x_true, W, b, w_val, b_val,
                                               w_idx, b_idx, out, gpart);
  final_minmax<<<dim3(8), 256, 0, stream>>>(gpart, out);
}